// Round 1
// baseline (275.770 us; speedup 1.0000x reference)
//
#include <hip/hip_runtime.h>

// TTLinear: out = x @ (core0 @ core1)^T + bias, exploiting rank-8 structure.
// Phase 1: y[t][r] = sum_i x[t][i] * core1[r][i]        (reads 128 MB x)
// Phase 2: out[t][o] = bias[o] + sum_r y[t][r]*core0[o][r] (writes 128 MB out)

#define TOKENS 8192
#define IN_F   4096
#define OUT_F  4096
#define RANK   8

// ---- Kernel 1: block = 256 threads (4 waves); each wave handles 2 tokens;
// block handles 8 tokens. Lane l reads float4 chunks at i = 4*(l + 64k),
// k = 0..15 -> fully coalesced 1 KB/instr on x. core1 float4 reused across
// the wave's 2 tokens in registers; core1 itself (128 KB) is L1/L2-resident.
__global__ __launch_bounds__(256) void tt_phase1(const float* __restrict__ x,
                                                 const float* __restrict__ core1,
                                                 float* __restrict__ y) {
    const int tid  = threadIdx.x;
    const int wave = tid >> 6;
    const int lane = tid & 63;
    const int t0   = blockIdx.x * 8 + wave * 2;

    const float* x0 = x + (size_t)t0 * IN_F;
    const float* x1 = x0 + IN_F;

    float acc0[RANK], acc1[RANK];
    #pragma unroll
    for (int r = 0; r < RANK; ++r) { acc0[r] = 0.f; acc1[r] = 0.f; }

    // unroll 4: 48 outstanding float4 loads per wave, bounded VGPR pressure
    #pragma unroll 4
    for (int k = 0; k < 16; ++k) {
        const int i = 4 * (lane + 64 * k);
        const float4 a0 = *(const float4*)(x0 + i);
        const float4 a1 = *(const float4*)(x1 + i);
        #pragma unroll
        for (int r = 0; r < RANK; ++r) {
            const float4 c = *(const float4*)(core1 + r * IN_F + i);
            acc0[r] += a0.x * c.x + a0.y * c.y + a0.z * c.z + a0.w * c.w;
            acc1[r] += a1.x * c.x + a1.y * c.y + a1.z * c.z + a1.w * c.w;
        }
    }

    // butterfly reduce across the 64-lane wave (all lanes end with the sum)
    #pragma unroll
    for (int r = 0; r < RANK; ++r) {
        #pragma unroll
        for (int off = 32; off > 0; off >>= 1) {
            acc0[r] += __shfl_xor(acc0[r], off, 64);
            acc1[r] += __shfl_xor(acc1[r], off, 64);
        }
    }

    if (lane == 0) {
        float4* yp = (float4*)(y + (size_t)t0 * RANK);
        yp[0] = make_float4(acc0[0], acc0[1], acc0[2], acc0[3]);
        yp[1] = make_float4(acc0[4], acc0[5], acc0[6], acc0[7]);
        yp[2] = make_float4(acc1[0], acc1[1], acc1[2], acc1[3]);
        yp[3] = make_float4(acc1[4], acc1[5], acc1[6], acc1[7]);
    }
}

// ---- Kernel 2: thread owns 4 consecutive o's (float4 store), keeps
// core0[4][8] + bias[4] in registers, loops over 32 tokens. Writes are
// coalesced float4 (consecutive tid -> consecutive 16 B). y loads are
// block-uniform (HW broadcast). Grid = 4 o-groups x 256 token-groups.
__global__ __launch_bounds__(256) void tt_phase2(const float* __restrict__ y,
                                                 const float* __restrict__ core0,
                                                 const float* __restrict__ bias,
                                                 float* __restrict__ out) {
    const int og    = blockIdx.x & 3;    // 4 groups of 1024 outputs
    const int tg    = blockIdx.x >> 2;   // 256 groups of 32 tokens
    const int o     = og * 1024 + threadIdx.x * 4;
    const int tbase = tg * 32;

    // core0 flat layout: [o][r], RANK=8 -> 4 o's = 32 consecutive floats
    float4 w[8];
    #pragma unroll
    for (int j = 0; j < 4; ++j) {
        w[2 * j]     = *(const float4*)(core0 + (o + j) * RANK);
        w[2 * j + 1] = *(const float4*)(core0 + (o + j) * RANK + 4);
    }
    const float4 b = *(const float4*)(bias + o);

    #pragma unroll 4
    for (int tt = 0; tt < 32; ++tt) {
        const int t = tbase + tt;
        const float4 y0 = *(const float4*)(y + t * RANK);
        const float4 y1 = *(const float4*)(y + t * RANK + 4);
        float4 c;
        c.x = b.x + y0.x * w[0].x + y0.y * w[0].y + y0.z * w[0].z + y0.w * w[0].w
                  + y1.x * w[1].x + y1.y * w[1].y + y1.z * w[1].z + y1.w * w[1].w;
        c.y = b.y + y0.x * w[2].x + y0.y * w[2].y + y0.z * w[2].z + y0.w * w[2].w
                  + y1.x * w[3].x + y1.y * w[3].y + y1.z * w[3].z + y1.w * w[3].w;
        c.z = b.z + y0.x * w[4].x + y0.y * w[4].y + y0.z * w[4].z + y0.w * w[4].w
                  + y1.x * w[5].x + y1.y * w[5].y + y1.z * w[5].z + y1.w * w[5].w;
        c.w = b.w + y0.x * w[6].x + y0.y * w[6].y + y0.z * w[6].z + y0.w * w[6].w
                  + y1.x * w[7].x + y1.y * w[7].y + y1.z * w[7].z + y1.w * w[7].w;
        *(float4*)(out + (size_t)t * OUT_F + o) = c;
    }
}

extern "C" void kernel_launch(void* const* d_in, const int* in_sizes, int n_in,
                              void* d_out, int out_size, void* d_ws, size_t ws_size,
                              hipStream_t stream) {
    const float* x     = (const float*)d_in[0];  // [8192, 4096]
    const float* core0 = (const float*)d_in[1];  // [1, 4096, 8] -> [o][r]
    const float* core1 = (const float*)d_in[2];  // [8, 4096, 1] -> [r][i]
    const float* bias  = (const float*)d_in[3];  // [4096]
    float* out = (float*)d_out;                  // [8192, 4096]
    float* y   = (float*)d_ws;                   // needs 8192*8*4 = 256 KB scratch

    tt_phase1<<<TOKENS / 8, 256, 0, stream>>>(x, core1, y);
    tt_phase2<<<(OUT_F / 1024) * (TOKENS / 32), 256, 0, stream>>>(y, core0, bias, out);
}